// Round 1
// 369.877 us; speedup vs baseline: 1.0666x; 1.0666x over previous
//
#include <hip/hip_runtime.h>

// GC-LSTM (SMPL) — fp32 I/O. Round 8: aggregation moved into MFMA.
// Identity (A X)W^T = A (X W^T) lets each step be two MFMAs:
//   Stage1: [P|Q] = [X|h](48x64pad) @ W1^T(192x64)   (W1 frags in REGISTERS)
//   Stage2: G2    = M'(48x96) @ [P;Q](96x..)         (M' = [adjacency | diag(cnt)],
//            entries {0..5} EXACT in bf16; M' frags in REGISTERS)
// Gate phase applies the inexact row scale in fp32: pre = iw_i*G2 + bias
// (iw*cnt = 1 folds the diag-Q path back to unit weight).
// Removes the whole fp32 A-gather phase (its ~46KB/step conflicted LDS reads
// + ~35% of VALU), removes XH, 5 -> 4 barriers/step. LDS 40,224 B -> 4 blk/CU.
// Kernel 2: projection, now with reg-staged global prefetch pipeline.

typedef short s16x8 __attribute__((ext_vector_type(8)));
typedef float f32x4 __attribute__((ext_vector_type(4)));

#define TPB 192
#define NB 2
// kernel-1 LDS byte offsets (total 40,224 <= 40,960 for 4 blocks/CU)
#define A_OFF    0        // PQt ushort[96][104] = 19,968 ; UO ushort[48][72] = 6,912 overlays
#define G_OFF    19968    // float [48][102] = 19,584
#define BIAS_OFF 39552    // float[96]
#define WG_OFF   39936    // float[72]
#define SMEM_SZ  40224

__device__ __forceinline__ float b2f(unsigned short u) {
    return __uint_as_float(((unsigned int)u) << 16);
}
__device__ __forceinline__ unsigned short f2b(float f) {
    unsigned int x = __float_as_uint(f);
    x = x + 0x7fffu + ((x >> 16) & 1u);   // RNE
    return (unsigned short)(x >> 16);
}
__device__ __forceinline__ unsigned int pk2(float a, float b) {
    return (unsigned int)f2b(a) | ((unsigned int)f2b(b) << 16);
}
__device__ __forceinline__ float frcp(float x) { return __builtin_amdgcn_rcpf(x); }
__device__ __forceinline__ float sigm(float x) {
    float t = __expf(-x);
    return frcp(1.0f + t);
}
__device__ __forceinline__ float tanh_(float x) {
    float xc = fmaxf(x, -30.f);
    float t = __expf(-2.f * xc);
    return (1.f - t) * frcp(1.f + t);
}

extern "C" __global__ void __launch_bounds__(TPB, 3)
gclstm_main(const float* __restrict__ src,
            const float* __restrict__ tgt,
            const float* __restrict__ We,
            const float* __restrict__ be,
            const float* __restrict__ Wxl,
            const float* __restrict__ bxl,
            const float* __restrict__ Wxr,
            const float* __restrict__ Whl,
            const float* __restrict__ bhl,
            const float* __restrict__ Whr,
            const float* __restrict__ wg,
            const float* __restrict__ bg,
            unsigned short* __restrict__ seqh)
{
    __shared__ __align__(16) char smem[SMEM_SZ];
    unsigned short* PQt = (unsigned short*)(smem + A_OFF);  // [96][104] bf16: [n][j']
    unsigned short* UO  = (unsigned short*)(smem + A_OFF);  // [48][72] bf16: k<24 X | 24..47 h | 48..71 zero
    float* G  = (float*)(smem + G_OFF);                     // [48][102] f32: G2[i][n]
    float* biasL = (float*)(smem + BIAS_OFF);
    float* wgL = (float*)(smem + WG_OFF);

    const int tid = threadIdx.x;
    const int b0 = blockIdx.x * NB;
    const int lane = tid & 63, wid = tid >> 6;      // 3 waves
    const int l15 = lane & 15, quad = lane >> 4;

    const int par[24] = {-1,0,0,0,1,2,3,4,5,6,7,8,9,9,9,12,13,14,16,17,18,19,20,21};

    // ---- stage-1 weight fragments in registers: wave wid owns col-tiles 4w..4w+3
    // n' < 96: l-path (Wxl/Whl -> P); n' >= 96: r-path (Wxr/Whr -> Q)
    // k: 0..23 X-features, 24..47 h-features, 48..63 zero pad
    s16x8 w1f[4][2];
#pragma unroll
    for (int cj = 0; cj < 4; ++cj) {
        int np = (wid * 4 + cj) * 16 + l15;
        int path = np >= 96 ? 1 : 0;
        int nn = np - path * 96;
        int g = nn / 24, d = nn - g * 24;
        const float* Wx = path ? Wxr : Wxl;
        const float* Wh = path ? Whr : Whl;
#pragma unroll
        for (int kt = 0; kt < 2; ++kt) {
            s16x8 f;
#pragma unroll
            for (int kk = 0; kk < 8; ++kk) {
                int k = kt * 32 + quad * 8 + kk;
                float v = 0.f;
                if (k < 24) v = Wx[g * 576 + d * 24 + k];
                else if (k < 48) v = Wh[g * 576 + d * 24 + (k - 24)];
                f[kk] = (short)f2b(v);
            }
            w1f[cj][kt] = f;
        }
    }

    // ---- M' fragments in registers (A-operand of stage 2), exact bf16 {0..5}
    // M'[i][j'] : j'<48 -> same-sample adjacency+self (0/1); j'>=48 -> diag cnt_i
    s16x8 mf[3][3];
#pragma unroll
    for (int rt = 0; rt < 3; ++rt) {
        int i = rt * 16 + l15;
        int si = i / 24, ji = i - si * 24;
        int cnt = 1 + (par[ji] >= 0 ? 1 : 0);
#pragma unroll
        for (int ch = 0; ch < 24; ++ch) cnt += (par[ch] == ji) ? 1 : 0;
        float cntf = (float)cnt;
#pragma unroll
        for (int kt = 0; kt < 3; ++kt) {
            s16x8 f;
#pragma unroll
            for (int kk = 0; kk < 8; ++kk) {
                int jp = kt * 32 + quad * 8 + kk;
                float v = 0.f;
                if (jp < 48) {
                    int sj = jp / 24, jj = jp - sj * 24;
                    if (sj == si && (jj == ji || par[jj] == ji || par[ji] == jj)) v = 1.f;
                } else {
                    if (jp - 48 == i) v = cntf;
                }
                f[kk] = (short)f2b(v);
            }
            mf[rt][kt] = f;
        }
    }

    if (tid < 96) biasL[tid] = bxl[tid] + bhl[tid] + bg[tid];
    if (tid < 72) wgL[tid] = wg[tid];

    // ---- per-thread task constants: task = row*12 + dp, 576 tasks = 3/thread
    int rowT[3], dpT[3];
    float iwT[3];
    long long seqbT[3];
#pragma unroll
    for (int t = 0; t < 3; ++t) {
        int task = tid + t * TPB;
        int row = task / 12, dp = task - row * 12;
        int j = row % 24;
        rowT[t] = row; dpT[t] = dp;
        int cnt = 1 + (par[j] >= 0 ? 1 : 0);
#pragma unroll
        for (int ch = 0; ch < 24; ++ch) cnt += (par[ch] == j) ? 1 : 0;
        iwT[t] = cnt == 2 ? 0.5f : cnt == 3 ? (1.f / 3.f) : cnt == 4 ? 0.25f : 0.2f;
        seqbT[t] = (long long)(b0 + row / 24) * 24 * 576 + (long long)j * 24 + 2 * dp;
    }

    float creg[3][2];
#pragma unroll
    for (int t = 0; t < 3; ++t) { creg[t][0] = 0.f; creg[t][1] = 0.f; }

    // ---- encoder init: X0 = relu(enc(src[:,0])), h = 0, pad = 0 ----
#pragma unroll
    for (int t = 0; t < 3; ++t) {
        int row = rowT[t], dp = dpT[t];
        int b = b0 + row / 24, j = row % 24;
        const float* sp = src + (size_t)b * 1728 + j * 3;
        float s0 = sp[0], s1 = sp[1], s2 = sp[2];
        int d = 2 * dp;
        float x0 = be[d] + s0 * We[d * 3] + s1 * We[d * 3 + 1] + s2 * We[d * 3 + 2];
        float x1 = be[d + 1] + s0 * We[d * 3 + 3] + s1 * We[d * 3 + 4] + s2 * We[d * 3 + 5];
        x0 = fmaxf(x0, 0.f); x1 = fmaxf(x1, 0.f);
        *(unsigned int*)(UO + row * 72 + d) = pk2(x0, x1);
        *(unsigned int*)(UO + row * 72 + 24 + d) = 0u;
        *(unsigned int*)(UO + row * 72 + 48 + d) = 0u;
    }
    __syncthreads();

    for (int s = 0; s < 48; ++s) {
        if (s == 24) {
            // decode inject: X = relu(enc(tgt[:,0])), h/c carried
#pragma unroll
            for (int t = 0; t < 3; ++t) {
                int row = rowT[t], dp = dpT[t];
                int b = b0 + row / 24, j = row % 24;
                const float* tp = tgt + (size_t)b * 1728 + j * 3;
                float s0 = tp[0], s1 = tp[1], s2 = tp[2];
                int d = 2 * dp;
                float x0 = be[d] + s0 * We[d * 3] + s1 * We[d * 3 + 1] + s2 * We[d * 3 + 2];
                float x1 = be[d + 1] + s0 * We[d * 3 + 3] + s1 * We[d * 3 + 4]
                         + s2 * We[d * 3 + 5];
                x0 = fmaxf(x0, 0.f); x1 = fmaxf(x1, 0.f);
                *(unsigned int*)(UO + row * 72 + d) = pk2(x0, x1);
            }
            __syncthreads();
        }

        // ---- A: stage-1 MFMA  [P|Q](48x192) = [X|h] @ W1^T (weights in regs)
        f32x4 acc1[3][4];
#pragma unroll
        for (int rt = 0; rt < 3; ++rt)
#pragma unroll
            for (int cj = 0; cj < 4; ++cj) acc1[rt][cj] = (f32x4)0.f;
#pragma unroll
        for (int kt = 0; kt < 2; ++kt)
#pragma unroll
            for (int rt = 0; rt < 3; ++rt) {
                s16x8 a = *(const s16x8*)(UO + (rt * 16 + l15) * 72 + kt * 32 + quad * 8);
#pragma unroll
                for (int cj = 0; cj < 4; ++cj)
                    acc1[rt][cj] = __builtin_amdgcn_mfma_f32_16x16x32_bf16(a, w1f[cj][kt], acc1[rt][cj], 0, 0, 0);
            }
        __syncthreads();   // (1) all UO reads done before PQt overlay write

        // ---- B: pack [P|Q] -> PQt bf16 [n][j']  (j' = j for P, 48+j for Q)
#pragma unroll
        for (int rt = 0; rt < 3; ++rt)
#pragma unroll
            for (int cj = 0; cj < 4; ++cj) {
                int np = (wid * 4 + cj) * 16 + l15;
                int r96 = np >= 96 ? np - 96 : np;
                int col = (np >= 96 ? 48 : 0) + rt * 16 + quad * 4;
                uint2 wv;
                wv.x = pk2(acc1[rt][cj][0], acc1[rt][cj][1]);
                wv.y = pk2(acc1[rt][cj][2], acc1[rt][cj][3]);
                *(uint2*)(PQt + r96 * 104 + col) = wv;
            }
        __syncthreads();   // (2)

        // ---- C: stage-2 MFMA  G2 = M' @ [P;Q]  + G write (f32, i-major)
        f32x4 acc2[3][2];
#pragma unroll
        for (int rt = 0; rt < 3; ++rt)
#pragma unroll
            for (int j2 = 0; j2 < 2; ++j2) acc2[rt][j2] = (f32x4)0.f;
#pragma unroll
        for (int kt = 0; kt < 3; ++kt)
#pragma unroll
            for (int j2 = 0; j2 < 2; ++j2) {
                s16x8 b = *(const s16x8*)(PQt + ((wid * 2 + j2) * 16 + l15) * 104 + kt * 32 + quad * 8);
#pragma unroll
                for (int rt = 0; rt < 3; ++rt) {
                    if (rt == 0 && kt == 2) continue;   // all-zero M' tile
                    acc2[rt][j2] = __builtin_amdgcn_mfma_f32_16x16x32_bf16(mf[rt][kt], b, acc2[rt][j2], 0, 0, 0);
                }
            }
#pragma unroll
        for (int rt = 0; rt < 3; ++rt)
#pragma unroll
            for (int j2 = 0; j2 < 2; ++j2) {
                int n = (wid * 2 + j2) * 16 + l15;
                int ib = rt * 16 + quad * 4;
#pragma unroll
                for (int r = 0; r < 4; ++r)
                    G[(ib + r) * 102 + n] = acc2[rt][j2][r];
            }
        __syncthreads();   // (3)

        // ---- E: gates (iw scale + bias in fp32), seq store, UO write-back
#pragma unroll
        for (int t = 0; t < 3; ++t) {
            int row = rowT[t], dp = dpT[t];
            float iw = iwT[t];
            const float* Gr = G + row * 102 + 2 * dp;
            float2 gi = *(const float2*)(Gr);
            float2 gf = *(const float2*)(Gr + 24);
            float2 gc = *(const float2*)(Gr + 48);
            float2 go = *(const float2*)(Gr + 72);
            float2 bi = *(const float2*)(biasL + 2 * dp);
            float2 bff = *(const float2*)(biasL + 24 + 2 * dp);
            float2 bcc = *(const float2*)(biasL + 48 + 2 * dp);
            float2 boo = *(const float2*)(biasL + 72 + 2 * dp);
            float2 wi = *(const float2*)(wgL + 2 * dp);
            float2 wf = *(const float2*)(wgL + 24 + 2 * dp);
            float2 wo = *(const float2*)(wgL + 48 + 2 * dp);
            float ov0, ov1, hv0, hv1;
            {
                float c = creg[t][0];
                float pi = fmaf(iw, gi.x, bi.x);
                float pf = fmaf(iw, gf.x, bff.x);
                float pc = fmaf(iw, gc.x, bcc.x);
                float po = fmaf(iw, go.x, boo.x);
                float iv = sigm(fmaf(wi.x, c, pi));
                float fv = sigm(fmaf(wf.x, c, pf));
                float cn = fmaf(fv, c, iv * tanh_(pc));
                float o  = sigm(fmaf(wo.x, cn, po));
                creg[t][0] = cn; ov0 = o; hv0 = o * tanh_(cn);
            }
            {
                float c = creg[t][1];
                float pi = fmaf(iw, gi.y, bi.y);
                float pf = fmaf(iw, gf.y, bff.y);
                float pc = fmaf(iw, gc.y, bcc.y);
                float po = fmaf(iw, go.y, boo.y);
                float iv = sigm(fmaf(wi.y, c, pi));
                float fv = sigm(fmaf(wf.y, c, pf));
                float cn = fmaf(fv, c, iv * tanh_(pc));
                float o  = sigm(fmaf(wo.y, cn, po));
                creg[t][1] = cn; ov1 = o; hv1 = o * tanh_(cn);
            }
            if (s >= 24) {
                long long off = seqbT[t] + (long long)(s - 24) * 576;
                *(unsigned int*)(seqh + off) = pk2(ov0, ov1);
            }
            // rewrite full UO row span (PQt writes clobbered the pad too)
            *(unsigned int*)(UO + row * 72 + 2 * dp) = pk2(ov0, ov1);
            *(unsigned int*)(UO + row * 72 + 24 + 2 * dp) = pk2(hv0, hv1);
            *(unsigned int*)(UO + row * 72 + 48 + 2 * dp) = 0u;
        }
        __syncthreads();   // (4)
    }
}

// Kernel 0: Wd (72x576 fp32) -> WdH (80x576 bf16, rows 72-79 zero)
extern "C" __global__ void __launch_bounds__(256)
wd_conv(const float* __restrict__ Wd, unsigned short* __restrict__ WdH)
{
    int i = blockIdx.x * 256 + threadIdx.x;
    if (i < 46080) {
        int n = i / 576, k = i - n * 576;
        WdH[i] = (n < 72) ? f2b(Wd[n * 576 + k]) : (unsigned short)0;
    }
}

// Kernel 2: out[row][o] = bd[o] + sum_k seq[row][k]*Wd[o][k]; bf16 MFMA.
// 768 blocks x 256 thr, 64 rows/block; K chunks of 96 with reg-staged prefetch:
// commit(regs->LDS); bar; issue next chunk's global loads; MFMA; bar.
template <int PRECONV>
__global__ void __launch_bounds__(256, 4)
gclstm_proj(const unsigned short* __restrict__ seqh,
            const unsigned short* __restrict__ WdH,
            const float* __restrict__ Wd,
            const float* __restrict__ bd,
            float* __restrict__ out)
{
    __shared__ unsigned short SQ[64 * 104];
    __shared__ unsigned short WH[80 * 104];

    const int tid = threadIdx.x;
    const int R0 = blockIdx.x * 64;
    const int lane = tid & 63, wid = tid >> 6;
    const int l15 = lane & 15, quad = lane >> 4;

    f32x4 acc[5];
#pragma unroll
    for (int j = 0; j < 5; ++j) acc[j] = (f32x4)0.f;

    if (PRECONV) {
        s16x8 sreg[3], wreg[4];
#pragma unroll
        for (int j = 0; j < 3; ++j) {
            int i = tid + j * 256; int r = i / 12, c8 = i - r * 12;
            sreg[j] = *(const s16x8*)(seqh + (size_t)(R0 + r) * 576 + (size_t)(c8 * 8));
        }
#pragma unroll
        for (int j = 0; j < 4; ++j) {
            int i = tid + j * 256;
            if (i < 960) { int n = i / 12, c8 = i - n * 12;
                wreg[j] = *(const s16x8*)(WdH + (size_t)n * 576 + (size_t)(c8 * 8)); }
        }
        for (int kc = 0; kc < 576; kc += 96) {
            // commit staged regs (compiler waits vmcnt here)
#pragma unroll
            for (int j = 0; j < 3; ++j) {
                int i = tid + j * 256; int r = i / 12, c8 = i - r * 12;
                *(s16x8*)(&SQ[r * 104 + c8 * 8]) = sreg[j];
            }
#pragma unroll
            for (int j = 0; j < 4; ++j) {
                int i = tid + j * 256;
                if (i < 960) { int n = i / 12, c8 = i - n * 12;
                    *(s16x8*)(&WH[n * 104 + c8 * 8]) = wreg[j]; }
            }
            __syncthreads();
            if (kc + 96 < 576) {    // issue next chunk; flies during MFMA
#pragma unroll
                for (int j = 0; j < 3; ++j) {
                    int i = tid + j * 256; int r = i / 12, c8 = i - r * 12;
                    sreg[j] = *(const s16x8*)(seqh + (size_t)(R0 + r) * 576 + (size_t)(kc + 96 + c8 * 8));
                }
#pragma unroll
                for (int j = 0; j < 4; ++j) {
                    int i = tid + j * 256;
                    if (i < 960) { int n = i / 12, c8 = i - n * 12;
                        wreg[j] = *(const s16x8*)(WdH + (size_t)n * 576 + (size_t)(kc + 96 + c8 * 8)); }
                }
            }
#pragma unroll
            for (int kt = 0; kt < 3; ++kt) {
                int koff = kt * 32 + quad * 8;
                s16x8 a = *(const s16x8*)(&SQ[(wid * 16 + l15) * 104 + koff]);
#pragma unroll
                for (int j = 0; j < 5; ++j) {
                    s16x8 b = *(const s16x8*)(&WH[(j * 16 + l15) * 104 + koff]);
                    acc[j] = __builtin_amdgcn_mfma_f32_16x16x32_bf16(a, b, acc[j], 0, 0, 0);
                }
            }
            __syncthreads();
        }
    } else {
        for (int kc = 0; kc < 576; kc += 96) {
            __syncthreads();
            for (int i = tid; i < 768; i += 256) {
                int r = i / 12, c8 = i - r * 12;
                *(s16x8*)(&SQ[r * 104 + c8 * 8]) =
                    *(const s16x8*)(seqh + (size_t)(R0 + r) * 576 + (size_t)(kc + c8 * 8));
            }
            for (int i = tid; i < 7680; i += 256) {
                int n = i / 96, kk = i - n * 96;
                float v = (n < 72) ? Wd[(size_t)n * 576 + (size_t)(kc + kk)] : 0.f;
                WH[n * 104 + kk] = f2b(v);
            }
            __syncthreads();
#pragma unroll
            for (int kt = 0; kt < 3; ++kt) {
                int koff = kt * 32 + quad * 8;
                s16x8 a = *(const s16x8*)(&SQ[(wid * 16 + l15) * 104 + koff]);
#pragma unroll
                for (int j = 0; j < 5; ++j) {
                    s16x8 b = *(const s16x8*)(&WH[(j * 16 + l15) * 104 + koff]);
                    acc[j] = __builtin_amdgcn_mfma_f32_16x16x32_bf16(a, b, acc[j], 0, 0, 0);
                }
            }
        }
    }

#pragma unroll
    for (int j = 0; j < 5; ++j) {
        int n = j * 16 + l15;
        if (n < 72) {
            float bv = bd[n];
            int rbase = R0 + wid * 16 + quad * 4;
#pragma unroll
            for (int r = 0; r < 4; ++r)
                out[(size_t)(rbase + r) * 72 + (size_t)n] = acc[j][r] + bv;
        }
    }
}

extern "C" void kernel_launch(void* const* d_in, const int* in_sizes, int n_in,
                              void* d_out, int out_size, void* d_ws, size_t ws_size,
                              hipStream_t stream)
{
    const float* src = (const float*)d_in[0];
    const float* tgt = (const float*)d_in[1];
    const float* We  = (const float*)d_in[2];
    const float* be  = (const float*)d_in[3];
    const float* Wxl = (const float*)d_in[4];
    const float* bxl = (const float*)d_in[5];
    const float* Wxr = (const float*)d_in[6];
    const float* Whl = (const float*)d_in[7];
    const float* bhl = (const float*)d_in[8];
    const float* Whr = (const float*)d_in[9];
    const float* wg  = (const float*)d_in[10];
    const float* bg  = (const float*)d_in[11];
    const float* Wd  = (const float*)d_in[12];
    const float* bd  = (const float*)d_in[13];
    float* out = (float*)d_out;                     // [2048][24][72] fp32
    unsigned short* seqh = (unsigned short*)d_ws;   // [2048][24][576] bf16

    const size_t seq_bytes = (size_t)2048 * 24 * 576 * 2;
    unsigned short* WdH = (unsigned short*)((char*)d_ws + seq_bytes);
    const bool preconv = ws_size >= seq_bytes + (size_t)80 * 576 * 2;

    if (preconv)
        wd_conv<<<dim3(180), dim3(256), 0, stream>>>(Wd, WdH);
    gclstm_main<<<dim3(1024), dim3(TPB), 0, stream>>>(
        src, tgt, We, be, Wxl, bxl, Wxr, Whl, bhl, Whr, wg, bg, seqh);
    if (preconv)
        gclstm_proj<1><<<dim3(768), dim3(256), 0, stream>>>(seqh, WdH, Wd, bd, out);
    else
        gclstm_proj<0><<<dim3(768), dim3(256), 0, stream>>>(seqh, nullptr, Wd, bd, out);
}